// Round 2
// baseline (412.885 us; speedup 1.0000x reference)
//
#include <hip/hip_runtime.h>
#include <math.h>

#define NV 778
#define KROW 2334   // NV*3

// ---------------- Kernel 1: SJ[k][j][c] = sum_v shapedirs[k][3v+c]*Jreg[v][j], J0[j][c] from v_template
__global__ void k1_sj(const float* __restrict__ shapedirs,
                      const float* __restrict__ v_template,
                      const float* __restrict__ Jreg,
                      float* __restrict__ SJ, float* __restrict__ J0)
{
    const int j = blockIdx.x / 3;
    const int c = blockIdx.x % 3;
    const int t = threadIdx.x;
    float acc[11];
#pragma unroll
    for (int k = 0; k < 11; ++k) acc[k] = 0.f;
    for (int v = t; v < NV; v += 64) {
        const float jr = Jreg[v*21 + j];
        acc[10] += v_template[v*3 + c] * jr;
#pragma unroll
        for (int k = 0; k < 10; ++k)
            acc[k] += shapedirs[k*KROW + v*3 + c] * jr;
    }
#pragma unroll
    for (int k = 0; k < 11; ++k) {
        float s = acc[k];
#pragma unroll
        for (int off = 32; off >= 1; off >>= 1) s += __shfl_down(s, off, 64);
        acc[k] = s;
    }
    if (t == 0) {
#pragma unroll
        for (int k = 0; k < 10; ++k) SJ[k*48 + j*3 + c] = acc[k];
        J0[j*3 + c] = acc[10];
    }
}

// ---------------- Kernel 2a: per (batch, joint) Rodrigues; writes R_g[b][16][9], coef[b][145]
__global__ void k2a_rot(const float* __restrict__ theta,
                        const float* __restrict__ wrist,
                        const float* __restrict__ hc,     // [10][45]
                        const float* __restrict__ hm,     // [45]
                        const float* __restrict__ beta,
                        float* __restrict__ R_g,
                        float* __restrict__ coef_g, int B)
{
    const int g = blockIdx.x * 256 + threadIdx.x;
    if (g >= B * 16) return;
    const int b = g >> 4, i = g & 15;
    float r0, r1, r2;
    if (i == 0) {
        r0 = wrist[b*3+0]; r1 = wrist[b*3+1]; r2 = wrist[b*3+2];
#pragma unroll
        for (int k = 0; k < 10; ++k) coef_g[(size_t)b*145 + k] = beta[b*10 + k];
    } else {
        const int col = (i-1)*3;
        float e0 = hm[col], e1 = hm[col+1], e2 = hm[col+2];
#pragma unroll
        for (int k = 0; k < 10; ++k) {
            const float th = theta[b*10 + k];
            e0 += th * hc[k*45 + col];
            e1 += th * hc[k*45 + col+1];
            e2 += th * hc[k*45 + col+2];
        }
        r0 = e0; r1 = e1; r2 = e2;
    }
    const float x_ = r0 + 1e-8f, y_ = r1 + 1e-8f, z_ = r2 + 1e-8f;
    const float angle = sqrtf(x_*x_ + y_*y_ + z_*z_);
    const float inv = 1.0f / angle;
    const float x = r0*inv, y = r1*inv, z = r2*inv;
    const float s = sinf(angle), c = cosf(angle);
    const float t1 = 1.0f - c;
    float R[9];
    R[0] = 1.f - t1*(y*y + z*z);
    R[1] = -s*z + t1*x*y;
    R[2] =  s*y + t1*x*z;
    R[3] =  s*z + t1*x*y;
    R[4] = 1.f - t1*(x*x + z*z);
    R[5] = -s*x + t1*y*z;
    R[6] = -s*y + t1*x*z;
    R[7] =  s*x + t1*y*z;
    R[8] = 1.f - t1*(x*x + y*y);
    float* Rd = R_g + (size_t)b*144 + i*9;
#pragma unroll
    for (int q = 0; q < 9; ++q) Rd[q] = R[q];
    if (i > 0) {
        float* pf = coef_g + (size_t)b*145 + 10 + (i-1)*9;
#pragma unroll
        for (int q = 0; q < 9; ++q)
            pf[q] = R[q] - ((q == 0 || q == 4 || q == 8) ? 1.f : 0.f);
    }
}

// ---------------- Kernel 2b: kinematic chain -> A[b][16][12] (rows [R|t-R*J])
__global__ void k2b_chain(const float* __restrict__ beta,
                          const float* __restrict__ R_g,
                          const float* __restrict__ SJ,
                          const float* __restrict__ J0,
                          float* __restrict__ A_g, int B)
{
    const int b = blockIdx.x * 64 + threadIdx.x;
    if (b >= B) return;
    float bt[10];
#pragma unroll
    for (int k = 0; k < 10; ++k) bt[k] = beta[b*10 + k];

    const float* Rb = R_g + (size_t)b*144;
    float* Ab = A_g + (size_t)b*192;

    auto jointJ = [&](int j, float* o) {
        float j0 = J0[j*3+0], j1 = J0[j*3+1], j2 = J0[j*3+2];
#pragma unroll
        for (int k = 0; k < 10; ++k) {
            j0 += bt[k] * SJ[k*48 + j*3 + 0];
            j1 += bt[k] * SJ[k*48 + j*3 + 1];
            j2 += bt[k] * SJ[k*48 + j*3 + 2];
        }
        o[0] = j0; o[1] = j1; o[2] = j2;
    };

    float G0R[9], J0v[3];
#pragma unroll
    for (int q = 0; q < 9; ++q) G0R[q] = Rb[q];
    jointJ(0, J0v);
#pragma unroll
    for (int r = 0; r < 3; ++r) {
        const float at = J0v[r] - (G0R[r*3+0]*J0v[0] + G0R[r*3+1]*J0v[1] + G0R[r*3+2]*J0v[2]);
        Ab[r*4+0] = G0R[r*3+0]; Ab[r*4+1] = G0R[r*3+1]; Ab[r*4+2] = G0R[r*3+2]; Ab[r*4+3] = at;
    }
    for (int ch = 0; ch < 5; ++ch) {
        float GpR[9], Gpt[3], Jp[3];
#pragma unroll
        for (int q = 0; q < 9; ++q) GpR[q] = G0R[q];
        Gpt[0] = J0v[0]; Gpt[1] = J0v[1]; Gpt[2] = J0v[2];
        Jp[0] = J0v[0]; Jp[1] = J0v[1]; Jp[2] = J0v[2];
        for (int s = 0; s < 3; ++s) {
            const int j = ch*3 + 1 + s;
            float Rl[9];
            const float* Rj = Rb + j*9;
#pragma unroll
            for (int q = 0; q < 9; ++q) Rl[q] = Rj[q];
            float Jc[3];
            jointJ(j, Jc);
            const float tl0 = Jc[0]-Jp[0], tl1 = Jc[1]-Jp[1], tl2 = Jc[2]-Jp[2];
            float GR[9], Gt[3];
#pragma unroll
            for (int r = 0; r < 3; ++r) {
#pragma unroll
                for (int cc = 0; cc < 3; ++cc)
                    GR[r*3+cc] = GpR[r*3+0]*Rl[0*3+cc] + GpR[r*3+1]*Rl[1*3+cc] + GpR[r*3+2]*Rl[2*3+cc];
                Gt[r] = GpR[r*3+0]*tl0 + GpR[r*3+1]*tl1 + GpR[r*3+2]*tl2 + Gpt[r];
            }
            float* Aj = Ab + j*12;
#pragma unroll
            for (int r = 0; r < 3; ++r) {
                const float at = Gt[r] - (GR[r*3+0]*Jc[0] + GR[r*3+1]*Jc[1] + GR[r*3+2]*Jc[2]);
                Aj[r*4+0] = GR[r*3+0]; Aj[r*4+1] = GR[r*3+1]; Aj[r*4+2] = GR[r*3+2]; Aj[r*4+3] = at;
            }
#pragma unroll
            for (int q = 0; q < 9; ++q) GpR[q] = GR[q];
            Gpt[0] = Gt[0]; Gpt[1] = Gt[1]; Gpt[2] = Gt[2];
            Jp[0] = Jc[0]; Jp[1] = Jc[1]; Jp[2] = Jc[2];
        }
    }
}

// ---------------- Kernel 3: fused blend-shapes + LBS + joint regression
// block = 256 threads handles BM=16 batches; vertices processed in 4 chunks of 256.
// Register budget is the whole game here (round-1 spilled ~330 MB of scratch):
//  - phase C owns only 6 persistent accumulators per lane (joint lt, joint 16+lt)
//  - phase B loads A 3xfloat4 at a time (peak ~90 VGPRs)
#define BM 16
#define CPAD 264   // vertex stride: 3*CPAD per batch = 792 ≡ 24 (mod 32) -> wave's 4 groups on distinct banks
__global__ __launch_bounds__(256, 2)
void k3_fused(const float* __restrict__ coef_g,   // [B][145]  (beta | pose_feature)
              const float* __restrict__ A_g,      // [B][16*12]
              const float* __restrict__ shapedirs,
              const float* __restrict__ posedirs,
              const float* __restrict__ v_template,
              const float* __restrict__ weights,  // [778][16]
              const float* __restrict__ Jreg,     // [778][21]
              float* __restrict__ out, int B)
{
    __shared__ __align__(16) float coef_s[145*BM];      // [k][m]
    __shared__ __align__(16) float A_s[BM*196];         // [m][jj*12+e], padded stride 196
    __shared__ __align__(16) float chunk_s[BM*3*CPAD];  // [m][c][vloc], padded
    __shared__ __align__(16) float jout_s[BM*63];

    const int t  = threadIdx.x;
    const int b0 = blockIdx.x * BM;

    {
        const int cmax = B*145 - 1;
        for (int idx = t; idx < 145*BM; idx += 256) {
            const int m = idx / 145, k = idx - m*145;
            coef_s[k*BM + m] = coef_g[min((size_t)b0*145 + idx, (size_t)cmax)];
        }
        const int amax = B*192 - 1;
        for (int idx = t; idx < BM*192; idx += 256) {
            const int m = idx / 192, e = idx - m*192;
            A_s[m*196 + e] = A_g[min((size_t)b0*192 + idx, (size_t)amax)];
        }
    }

    const int mt = t >> 4;   // batch index for phases B/C
    const int lt = t & 15;   // lane within 16-thread group

    // persistent joint accumulators: joint lt, and joint 16+lt when lt<5
    float ja0 = 0.f, ja1 = 0.f, ja2 = 0.f;
    float jb0 = 0.f, jb1 = 0.f, jb2 = 0.f;

    __syncthreads();

    for (int chunk = 0; chunk < 4; ++chunk) {
        const int vbase = chunk * 256;
        const int nv = min(256, NV - vbase);   // 256,256,256,10
        const int v = vbase + t;

        // ---- phase A: K=145 blend-shape GEMM, this thread's vertex x 16 batches
        if (t < nv) {
            float a0[BM], a1[BM], a2[BM];
            const float vt0 = v_template[v*3+0];
            const float vt1 = v_template[v*3+1];
            const float vt2 = v_template[v*3+2];
#pragma unroll
            for (int m = 0; m < BM; ++m) { a0[m] = vt0; a1[m] = vt1; a2[m] = vt2; }
            const float4* cs4 = (const float4*)coef_s;
            const float* sp = shapedirs + v*3;
#pragma unroll
            for (int k = 0; k < 10; ++k) {
                const float s0 = sp[0], s1 = sp[1], s2 = sp[2];
                sp += KROW;
#pragma unroll
                for (int q = 0; q < 4; ++q) {
                    const float4 cc = cs4[k*4 + q];
                    a0[4*q+0] += cc.x*s0; a1[4*q+0] += cc.x*s1; a2[4*q+0] += cc.x*s2;
                    a0[4*q+1] += cc.y*s0; a1[4*q+1] += cc.y*s1; a2[4*q+1] += cc.y*s2;
                    a0[4*q+2] += cc.z*s0; a1[4*q+2] += cc.z*s1; a2[4*q+2] += cc.z*s2;
                    a0[4*q+3] += cc.w*s0; a1[4*q+3] += cc.w*s1; a2[4*q+3] += cc.w*s2;
                }
            }
            const float* pp = posedirs + v*3;
#pragma unroll 3
            for (int k = 0; k < 135; ++k) {
                const float s0 = pp[0], s1 = pp[1], s2 = pp[2];
                pp += KROW;
#pragma unroll
                for (int q = 0; q < 4; ++q) {
                    const float4 cc = cs4[(10+k)*4 + q];
                    a0[4*q+0] += cc.x*s0; a1[4*q+0] += cc.x*s1; a2[4*q+0] += cc.x*s2;
                    a0[4*q+1] += cc.y*s0; a1[4*q+1] += cc.y*s1; a2[4*q+1] += cc.y*s2;
                    a0[4*q+2] += cc.z*s0; a1[4*q+2] += cc.z*s1; a2[4*q+2] += cc.z*s2;
                    a0[4*q+3] += cc.w*s0; a1[4*q+3] += cc.w*s1; a2[4*q+3] += cc.w*s2;
                }
            }
#pragma unroll
            for (int m = 0; m < BM; ++m) {
                chunk_s[(m*3+0)*CPAD + t] = a0[m];
                chunk_s[(m*3+1)*CPAD + t] = a1[m];
                chunk_s[(m*3+2)*CPAD + t] = a2[m];
            }
        }
        __syncthreads();

        // ---- phase B: T = sum_jj w*A, verts = T*vph (in-place in chunk_s)
        for (int rnd = 0; rnd < 4; ++rnd) {
            if (rnd*64 >= nv) break;   // uniform skip for tail chunk
            float T[4][12];
#pragma unroll
            for (int vv = 0; vv < 4; ++vv)
#pragma unroll
                for (int e = 0; e < 12; ++e) T[vv][e] = 0.f;
#pragma unroll
            for (int jq = 0; jq < 4; ++jq) {
                float4 wv[4];
#pragma unroll
                for (int vv = 0; vv < 4; ++vv) {
                    const int vloc = lt + 16*(rnd*4 + vv);
                    const int vg = min(vbase + vloc, NV - 1);
                    wv[vv] = *(const float4*)(weights + vg*16 + jq*4);
                }
                const float4* Am = (const float4*)(A_s + mt*196 + jq*48);
#pragma unroll
                for (int e = 0; e < 4; ++e) {
                    const float4 ax = Am[e*3+0];
                    const float4 ay = Am[e*3+1];
                    const float4 az = Am[e*3+2];
#pragma unroll
                    for (int vv = 0; vv < 4; ++vv) {
                        const float we = (e == 0) ? wv[vv].x : (e == 1) ? wv[vv].y
                                       : (e == 2) ? wv[vv].z : wv[vv].w;
                        T[vv][0] += we*ax.x; T[vv][1]  += we*ax.y;
                        T[vv][2] += we*ax.z; T[vv][3]  += we*ax.w;
                        T[vv][4] += we*ay.x; T[vv][5]  += we*ay.y;
                        T[vv][6] += we*ay.z; T[vv][7]  += we*ay.w;
                        T[vv][8] += we*az.x; T[vv][9]  += we*az.y;
                        T[vv][10]+= we*az.z; T[vv][11] += we*az.w;
                    }
                }
            }
#pragma unroll
            for (int vv = 0; vv < 4; ++vv) {
                const int vloc = lt + 16*(rnd*4 + vv);
                if (vloc < nv) {
                    const float hx = chunk_s[(mt*3+0)*CPAD + vloc];
                    const float hy = chunk_s[(mt*3+1)*CPAD + vloc];
                    const float hz = chunk_s[(mt*3+2)*CPAD + vloc];
                    const float vx = T[vv][0]*hx + T[vv][1]*hy + T[vv][2]*hz  + T[vv][3];
                    const float vy = T[vv][4]*hx + T[vv][5]*hy + T[vv][6]*hz  + T[vv][7];
                    const float vz = T[vv][8]*hx + T[vv][9]*hy + T[vv][10]*hz + T[vv][11];
                    chunk_s[(mt*3+0)*CPAD + vloc] = vx;
                    chunk_s[(mt*3+1)*CPAD + vloc] = vy;
                    chunk_s[(mt*3+2)*CPAD + vloc] = vz;
                }
            }
        }
        __syncthreads();

        // ---- phase C: joint regression — lane lt owns joint lt (and 16+lt if lt<5),
        // iterates ALL chunk vertices (LDS reads broadcast within group; Jreg row
        // identical across the wave's 4 groups -> one 64B segment per load).
        for (int i = 0; i < nv; ++i) {
            const float vx = chunk_s[(mt*3+0)*CPAD + i];
            const float vy = chunk_s[(mt*3+1)*CPAD + i];
            const float vz = chunk_s[(mt*3+2)*CPAD + i];
            const float* jr = Jreg + (size_t)(vbase + i)*21;
            const float j0 = jr[lt];
            ja0 += j0*vx; ja1 += j0*vy; ja2 += j0*vz;
            if (lt < 5) {
                const float j1v = jr[16 + lt];
                jb0 += j1v*vx; jb1 += j1v*vy; jb2 += j1v*vz;
            }
        }
        __syncthreads();
    }

    // write accumulated joints (no cross-lane reduce needed: each lane owns its joints)
    jout_s[mt*63 + lt*3 + 0] = ja0;
    jout_s[mt*63 + lt*3 + 1] = ja1;
    jout_s[mt*63 + lt*3 + 2] = ja2;
    if (lt < 5) {
        jout_s[mt*63 + (16+lt)*3 + 0] = jb0;
        jout_s[mt*63 + (16+lt)*3 + 1] = jb1;
        jout_s[mt*63 + (16+lt)*3 + 2] = jb2;
    }
    __syncthreads();
    const size_t obase = (size_t)b0 * 63;
    const size_t omax = (size_t)B * 63;
    for (int idx = t; idx < BM*63; idx += 256) {
        if (obase + idx < omax) out[obase + idx] = jout_s[idx];
    }
}

extern "C" void kernel_launch(void* const* d_in, const int* in_sizes, int n_in,
                              void* d_out, int out_size, void* d_ws, size_t ws_size,
                              hipStream_t stream) {
    (void)n_in; (void)out_size; (void)ws_size;
    const float* beta       = (const float*)d_in[0];
    const float* theta      = (const float*)d_in[1];
    const float* wrist      = (const float*)d_in[2];
    const float* v_template = (const float*)d_in[3];
    const float* shapedirs  = (const float*)d_in[4];
    const float* posedirs   = (const float*)d_in[5];
    const float* Jreg       = (const float*)d_in[6];
    const float* hc         = (const float*)d_in[7];
    const float* hm         = (const float*)d_in[8];
    const float* weights    = (const float*)d_in[9];
    float* out = (float*)d_out;
    const int B = in_sizes[0] / 10;

    float* ws   = (float*)d_ws;
    float* SJ   = ws;                       // 480
    float* J0   = ws + 480;                 // 48
    float* R_g  = ws + 528;                 // B*144
    float* coef = R_g + (size_t)B*144;      // B*145
    float* A_g  = coef + (size_t)B*145;     // B*192

    k1_sj<<<48, 64, 0, stream>>>(shapedirs, v_template, Jreg, SJ, J0);
    k2a_rot<<<(B*16 + 255)/256, 256, 0, stream>>>(theta, wrist, hc, hm, beta, R_g, coef, B);
    k2b_chain<<<(B + 63)/64, 64, 0, stream>>>(beta, R_g, SJ, J0, A_g, B);
    k3_fused<<<(B + BM - 1)/BM, 256, 0, stream>>>(coef, A_g, shapedirs, posedirs,
                                                  v_template, weights, Jreg, out, B);
}

// Round 3
// 203.036 us; speedup vs baseline: 2.0336x; 2.0336x over previous
//
#include <hip/hip_runtime.h>
#include <math.h>

#define NV 778
#define KROW 2334     // NV*3
#define KTOT 146      // 10 beta + 135 pose-feature + 1 const(template)
#define NCOL 1008     // 21 j * 16 jj * 3 c
#define NPART 4       // v-splits in precompute

// ======================= kA: batch-independent precompute ====================
// bid <  48  : SJ[k][j][c], J0[j][c]   (chain joint regressors, j<16)
// bid <  384 : Q[j*16+jj] = sum_v Jreg[v][j]*wgt[v][jj]
// else       : W2[v][j*16+jj] = Jreg[v][j]*wgt[v][jj]
__global__ __launch_bounds__(64) void kA_pre(const float* __restrict__ shapedirs,
                                             const float* __restrict__ v_template,
                                             const float* __restrict__ Jreg,
                                             const float* __restrict__ wgt,
                                             float* __restrict__ SJ, float* __restrict__ J0,
                                             float* __restrict__ Q,  float* __restrict__ W2)
{
    const int bid = blockIdx.x;
    const int t = threadIdx.x;
    if (bid < 48) {
        const int j = bid / 3, c = bid % 3;
        float acc[11];
#pragma unroll
        for (int k = 0; k < 11; ++k) acc[k] = 0.f;
        for (int v = t; v < NV; v += 64) {
            const float jr = Jreg[v*21 + j];
            acc[10] += v_template[v*3 + c] * jr;
#pragma unroll
            for (int k = 0; k < 10; ++k)
                acc[k] += shapedirs[(size_t)k*KROW + v*3 + c] * jr;
        }
#pragma unroll
        for (int k = 0; k < 11; ++k) {
            float s = acc[k];
#pragma unroll
            for (int off = 32; off >= 1; off >>= 1) s += __shfl_down(s, off, 64);
            acc[k] = s;
        }
        if (t == 0) {
#pragma unroll
            for (int k = 0; k < 10; ++k) SJ[k*48 + j*3 + c] = acc[k];
            J0[j*3 + c] = acc[10];
        }
    } else if (bid < 384) {
        const int m = bid - 48, j = m >> 4, jj = m & 15;
        float s = 0.f;
        for (int v = t; v < NV; v += 64)
            s += Jreg[v*21 + j] * wgt[v*16 + jj];
#pragma unroll
        for (int off = 32; off >= 1; off >>= 1) s += __shfl_down(s, off, 64);
        if (t == 0) Q[m] = s;
    } else {
        const int gi = (bid - 384)*64 + t;
        if (gi < NV*336) {
            const int v = gi / 336, m = gi % 336;
            const int j = m >> 4, jj = m & 15;
            W2[gi] = Jreg[v*21 + j] * wgt[v*16 + jj];
        }
    }
}

// ======================= k_pre2: PK partials (batch-independent) =============
// block = (j, c, s): PKpart[s][k][j*48 + jj*3 + c] = sum_{v in split s} dirsX[k][3v+c]*W2[v][j*16+jj]
__global__ __launch_bounds__(192) void k_pre2(const float* __restrict__ shapedirs,
                                              const float* __restrict__ posedirs,
                                              const float* __restrict__ v_template,
                                              const float* __restrict__ W2,
                                              float* __restrict__ PKpart)
{
    const int bid = blockIdx.x;          // 252 = 21 j * 3 c * 4 s
    const int j = bid % 21;
    const int c = (bid / 21) % 3;
    const int s = bid / 63;
    const int k = threadIdx.x;
    if (k >= KTOT) return;
    const float* drow = (k < 10)  ? shapedirs + (size_t)k*KROW
                      : (k < 145) ? posedirs + (size_t)(k-10)*KROW
                                  : v_template;
    float acc[16];
#pragma unroll
    for (int q = 0; q < 16; ++q) acc[q] = 0.f;
    const int v0 = s*195, v1 = min(NV, v0 + 195);
    for (int v = v0; v < v1; ++v) {
        const float d = drow[3*v + c];
        const float4* wq = (const float4*)(W2 + (size_t)v*336 + j*16);  // uniform -> s_load
        const float4 w0 = wq[0], w1 = wq[1], w2 = wq[2], w3 = wq[3];
        acc[0]  += d*w0.x; acc[1]  += d*w0.y; acc[2]  += d*w0.z; acc[3]  += d*w0.w;
        acc[4]  += d*w1.x; acc[5]  += d*w1.y; acc[6]  += d*w1.z; acc[7]  += d*w1.w;
        acc[8]  += d*w2.x; acc[9]  += d*w2.y; acc[10] += d*w2.z; acc[11] += d*w2.w;
        acc[12] += d*w3.x; acc[13] += d*w3.y; acc[14] += d*w3.z; acc[15] += d*w3.w;
    }
    float* o = PKpart + ((size_t)s*KTOT + k)*NCOL + j*48 + c;
#pragma unroll
    for (int q = 0; q < 16; ++q) o[q*3] = acc[q];
}

// ======================= k_p3: reduce partials -> PK[146][1008] ==============
__global__ void k_p3(const float* __restrict__ PKpart, float* __restrict__ PK)
{
    const int idx = blockIdx.x*256 + threadIdx.x;
    if (idx < KTOT*NCOL) {
        PK[idx] = PKpart[idx] + PKpart[KTOT*NCOL + idx]
                + PKpart[2*KTOT*NCOL + idx] + PKpart[3*KTOT*NCOL + idx];
    }
}

// ======================= k2: rodrigues + coefT + kinematic chain =============
// block = 16 batches x 16 joints. Writes coefT[k][B] (k<146, row 145 = 1.0) and A_g[b][192].
__global__ __launch_bounds__(256) void k2_pose(const float* __restrict__ beta,
                                               const float* __restrict__ theta,
                                               const float* __restrict__ wrist,
                                               const float* __restrict__ hc,
                                               const float* __restrict__ hm,
                                               const float* __restrict__ SJ,
                                               const float* __restrict__ J0,
                                               float* __restrict__ coefT,
                                               float* __restrict__ A_g, int B)
{
    __shared__ float Rs[16*144];    // [b_loc][i*9+q]
    __shared__ float cls[16*148];   // [b_loc][k]
    const int t = threadIdx.x;
    const int bl = t >> 4, i = t & 15;
    const int b = blockIdx.x*16 + bl;

    float r0, r1, r2;
    if (i == 0) {
        r0 = wrist[b*3+0]; r1 = wrist[b*3+1]; r2 = wrist[b*3+2];
#pragma unroll
        for (int k = 0; k < 10; ++k) cls[bl*148 + k] = beta[b*10 + k];
        cls[bl*148 + 145] = 1.0f;
    } else {
        const int col = (i-1)*3;
        float e0 = hm[col], e1 = hm[col+1], e2 = hm[col+2];
#pragma unroll
        for (int k = 0; k < 10; ++k) {
            const float th = theta[b*10 + k];
            e0 += th * hc[k*45 + col];
            e1 += th * hc[k*45 + col+1];
            e2 += th * hc[k*45 + col+2];
        }
        r0 = e0; r1 = e1; r2 = e2;
    }
    // rodrigues (matches reference: eps added per-component before norm; axis uses raw r)
    const float x_ = r0 + 1e-8f, y_ = r1 + 1e-8f, z_ = r2 + 1e-8f;
    const float angle = sqrtf(x_*x_ + y_*y_ + z_*z_);
    const float inv = 1.0f / angle;
    const float x = r0*inv, y = r1*inv, z = r2*inv;
    const float sn = sinf(angle), cs = cosf(angle);
    const float t1 = 1.0f - cs;
    float R[9];
    R[0] = 1.f - t1*(y*y + z*z);
    R[1] = -sn*z + t1*x*y;
    R[2] =  sn*y + t1*x*z;
    R[3] =  sn*z + t1*x*y;
    R[4] = 1.f - t1*(x*x + z*z);
    R[5] = -sn*x + t1*y*z;
    R[6] = -sn*y + t1*x*z;
    R[7] =  sn*x + t1*y*z;
    R[8] = 1.f - t1*(x*x + y*y);
#pragma unroll
    for (int q = 0; q < 9; ++q) Rs[bl*144 + i*9 + q] = R[q];
    if (i > 0) {
#pragma unroll
        for (int q = 0; q < 9; ++q)
            cls[bl*148 + 10 + (i-1)*9 + q] = R[q] - ((q==0||q==4||q==8) ? 1.f : 0.f);
    }
    __syncthreads();

    // transposed coefT store: row t, 16 batch columns
    if (t < KTOT) {
        float tmp[16];
#pragma unroll
        for (int m = 0; m < 16; ++m) tmp[m] = cls[m*148 + t];
        float4* dst = (float4*)(coefT + (size_t)t*B + blockIdx.x*16);
        dst[0] = make_float4(tmp[0],  tmp[1],  tmp[2],  tmp[3]);
        dst[1] = make_float4(tmp[4],  tmp[5],  tmp[6],  tmp[7]);
        dst[2] = make_float4(tmp[8],  tmp[9],  tmp[10], tmp[11]);
        dst[3] = make_float4(tmp[12], tmp[13], tmp[14], tmp[15]);
    }

    // kinematic chain: one thread per batch (t<16)
    if (t < 16) {
        const int b2 = blockIdx.x*16 + t;
        float bt[10];
#pragma unroll
        for (int k = 0; k < 10; ++k) bt[k] = beta[b2*10 + k];
        const float* Rb = Rs + t*144;
        float4* Ab = (float4*)(A_g + (size_t)b2*192);

        auto jointJ = [&](int j, float* o) {
            float j0 = J0[j*3+0], j1 = J0[j*3+1], j2 = J0[j*3+2];
#pragma unroll
            for (int k = 0; k < 10; ++k) {
                j0 += bt[k] * SJ[k*48 + j*3 + 0];
                j1 += bt[k] * SJ[k*48 + j*3 + 1];
                j2 += bt[k] * SJ[k*48 + j*3 + 2];
            }
            o[0] = j0; o[1] = j1; o[2] = j2;
        };

        float G0R[9], J0v[3];
#pragma unroll
        for (int q = 0; q < 9; ++q) G0R[q] = Rb[q];
        jointJ(0, J0v);
#pragma unroll
        for (int r = 0; r < 3; ++r) {
            const float at = J0v[r] - (G0R[r*3+0]*J0v[0] + G0R[r*3+1]*J0v[1] + G0R[r*3+2]*J0v[2]);
            Ab[r] = make_float4(G0R[r*3+0], G0R[r*3+1], G0R[r*3+2], at);
        }
        for (int ch = 0; ch < 5; ++ch) {
            float GpR[9], Gpt[3], Jp[3];
#pragma unroll
            for (int q = 0; q < 9; ++q) GpR[q] = G0R[q];
            Gpt[0]=J0v[0]; Gpt[1]=J0v[1]; Gpt[2]=J0v[2];
            Jp[0]=J0v[0];  Jp[1]=J0v[1];  Jp[2]=J0v[2];
            for (int s = 0; s < 3; ++s) {
                const int j = ch*3 + 1 + s;
                float Rl[9];
                const float* Rj = Rb + j*9;
#pragma unroll
                for (int q = 0; q < 9; ++q) Rl[q] = Rj[q];
                float Jc[3];
                jointJ(j, Jc);
                const float tl0 = Jc[0]-Jp[0], tl1 = Jc[1]-Jp[1], tl2 = Jc[2]-Jp[2];
                float GR[9], Gt[3];
#pragma unroll
                for (int r = 0; r < 3; ++r) {
#pragma unroll
                    for (int cc = 0; cc < 3; ++cc)
                        GR[r*3+cc] = GpR[r*3+0]*Rl[0*3+cc] + GpR[r*3+1]*Rl[1*3+cc] + GpR[r*3+2]*Rl[2*3+cc];
                    Gt[r] = GpR[r*3+0]*tl0 + GpR[r*3+1]*tl1 + GpR[r*3+2]*tl2 + Gpt[r];
                }
#pragma unroll
                for (int r = 0; r < 3; ++r) {
                    const float at = Gt[r] - (GR[r*3+0]*Jc[0] + GR[r*3+1]*Jc[1] + GR[r*3+2]*Jc[2]);
                    Ab[j*3 + r] = make_float4(GR[r*3+0], GR[r*3+1], GR[r*3+2], at);
                }
#pragma unroll
                for (int q = 0; q < 9; ++q) GpR[q] = GR[q];
                Gpt[0]=Gt[0]; Gpt[1]=Gt[1]; Gpt[2]=Gt[2];
                Jp[0]=Jc[0];  Jp[1]=Jc[1];  Jp[2]=Jc[2];
            }
        }
    }
}

// ======================= k3: P-GEMM (B x 1008 x 146) + fused joint epilogue ==
// grid (B/128, 21). Wave ci = t>>6 owns col-quads {4ci, 16+4ci, 32+4ci} of the
// 48-col j-strip -> PK reads are wave-uniform (s_load, zero LDS in K-loop).
// coef read as one coalesced float2 per k. 24 FMA / k / thread.
__global__ __launch_bounds__(256) void k3_gemm(const float* __restrict__ coefT,
                                               const float* __restrict__ PK,
                                               const float* __restrict__ A_g,
                                               const float* __restrict__ Q,
                                               float* __restrict__ out, int B)
{
    __shared__ float Pex[128*49];
    const int t  = threadIdx.x;
    const int b0 = blockIdx.x * 128;
    const int j  = blockIdx.y;
    const int ci = __builtin_amdgcn_readfirstlane(t >> 6);
    const int bi = t & 63;

    float acc[3][4][2];
#pragma unroll
    for (int u = 0; u < 3; ++u)
#pragma unroll
        for (int cc = 0; cc < 4; ++cc) { acc[u][cc][0] = 0.f; acc[u][cc][1] = 0.f; }

    const float* pkbase = PK + j*48 + 4*ci;     // uniform
    const float* cbase  = coefT + b0 + 2*bi;    // per-lane, coalesced

#pragma unroll 2
    for (int k = 0; k < KTOT; ++k) {
        const float2 c2 = *(const float2*)(cbase + (size_t)k*B);
        const float* pr = pkbase + (size_t)k*NCOL;
        const float4 p0 = *(const float4*)(pr);        // s_load_dwordx4
        const float4 p1 = *(const float4*)(pr + 16);
        const float4 p2 = *(const float4*)(pr + 32);
        acc[0][0][0] += p0.x*c2.x; acc[0][0][1] += p0.x*c2.y;
        acc[0][1][0] += p0.y*c2.x; acc[0][1][1] += p0.y*c2.y;
        acc[0][2][0] += p0.z*c2.x; acc[0][2][1] += p0.z*c2.y;
        acc[0][3][0] += p0.w*c2.x; acc[0][3][1] += p0.w*c2.y;
        acc[1][0][0] += p1.x*c2.x; acc[1][0][1] += p1.x*c2.y;
        acc[1][1][0] += p1.y*c2.x; acc[1][1][1] += p1.y*c2.y;
        acc[1][2][0] += p1.z*c2.x; acc[1][2][1] += p1.z*c2.y;
        acc[1][3][0] += p1.w*c2.x; acc[1][3][1] += p1.w*c2.y;
        acc[2][0][0] += p2.x*c2.x; acc[2][0][1] += p2.x*c2.y;
        acc[2][1][0] += p2.y*c2.x; acc[2][1][1] += p2.y*c2.y;
        acc[2][2][0] += p2.z*c2.x; acc[2][2][1] += p2.z*c2.y;
        acc[2][3][0] += p2.w*c2.x; acc[2][3][1] += p2.w*c2.y;
    }

#pragma unroll
    for (int u = 0; u < 3; ++u)
#pragma unroll
        for (int cc = 0; cc < 4; ++cc)
#pragma unroll
            for (int e = 0; e < 2; ++e)
                Pex[(2*bi + e)*49 + 16*u + 4*ci + cc] = acc[u][cc][e];
    __syncthreads();

    if (t < 128) {
        const int b = b0 + t;
        const float4* Ab = ((const float4*)A_g) + (size_t)b*48;
        const float* Pr = Pex + t*49;
        float jx = 0.f, jy = 0.f, jz = 0.f;
#pragma unroll
        for (int jj = 0; jj < 16; ++jj) {
            const float qv = Q[j*16 + jj];              // uniform -> s_load
            const float4 a0 = Ab[jj*3+0];
            const float4 a1 = Ab[jj*3+1];
            const float4 a2 = Ab[jj*3+2];
            const float px = Pr[jj*3+0], py = Pr[jj*3+1], pz = Pr[jj*3+2];
            jx += a0.x*px + a0.y*py + a0.z*pz + a0.w*qv;
            jy += a1.x*px + a1.y*py + a1.z*pz + a1.w*qv;
            jz += a2.x*px + a2.y*py + a2.z*pz + a2.w*qv;
        }
        float* op = out + (size_t)b*63 + j*3;
        op[0] = jx; op[1] = jy; op[2] = jz;
    }
}

// ============================================================================
extern "C" void kernel_launch(void* const* d_in, const int* in_sizes, int n_in,
                              void* d_out, int out_size, void* d_ws, size_t ws_size,
                              hipStream_t stream) {
    (void)n_in; (void)out_size; (void)ws_size;
    const float* beta       = (const float*)d_in[0];
    const float* theta      = (const float*)d_in[1];
    const float* wrist      = (const float*)d_in[2];
    const float* v_template = (const float*)d_in[3];
    const float* shapedirs  = (const float*)d_in[4];
    const float* posedirs   = (const float*)d_in[5];
    const float* Jreg       = (const float*)d_in[6];
    const float* hc         = (const float*)d_in[7];
    const float* hm         = (const float*)d_in[8];
    const float* wgt        = (const float*)d_in[9];
    float* out = (float*)d_out;
    const int B = in_sizes[0] / 10;

    // workspace layout (floats, offsets rounded to 64)
    float* ws = (float*)d_ws;
    size_t off = 0;
    auto alloc = [&](size_t n) { float* p = ws + off; off = (off + n + 63) & ~(size_t)63; return p; };
    float* SJ     = alloc(480);
    float* J0     = alloc(48);
    float* Q      = alloc(336);
    float* W2     = alloc((size_t)NV*336);
    float* PKpart = alloc((size_t)NPART*KTOT*NCOL);
    float* PK     = alloc((size_t)KTOT*NCOL);
    float* coefT  = alloc((size_t)KTOT*B);
    float* A_g    = alloc((size_t)B*192);

    const int w2_blocks = (NV*336 + 63)/64;
    kA_pre<<<384 + w2_blocks, 64, 0, stream>>>(shapedirs, v_template, Jreg, wgt, SJ, J0, Q, W2);
    k2_pose<<<(B + 15)/16, 256, 0, stream>>>(beta, theta, wrist, hc, hm, SJ, J0, coefT, A_g, B);
    k_pre2<<<21*3*NPART, 192, 0, stream>>>(shapedirs, posedirs, v_template, W2, PKpart);
    k_p3<<<(KTOT*NCOL + 255)/256, 256, 0, stream>>>(PKpart, PK);
    k3_gemm<<<dim3(B/128, 21), 256, 0, stream>>>(coefT, PK, A_g, Q, out, B);
}